// Round 4
// baseline (771.352 us; speedup 1.0000x reference)
//
#include <hip/hip_runtime.h>
#include <hip/hip_bf16.h>

#define N_NODES 100000
#define IN_F    128
#define OUT_F   64
#define ROWS_PER_BLK 32
#define INV_KEEP (1.0f / 0.9f)

#define RPB_LOG 7                 // rows per bucket = 128
#define RPB (1 << RPB_LOG)
#define NB  ((N_NODES + RPB - 1) / RPB)   // 782 buckets
#define BIN_CHUNK 4096
#define BIN_BS 1024

// ---------------------------------------------------------------------------
// Kernel 1: hidden = dropout(x @ W + b) -> bf16 [N_NODES x OUT_F] in ws.
// ---------------------------------------------------------------------------
__global__ __launch_bounds__(256) void gemm_dropout_kernel(
    const float* __restrict__ x, const float* __restrict__ w,
    const float* __restrict__ bias, const void* __restrict__ mask,
    ushort* __restrict__ hidden) {
  __shared__ float wlds[IN_F * OUT_F];          // 32 KB
  __shared__ float xlds[ROWS_PER_BLK * IN_F];   // 16 KB
  __shared__ int mask_is_u8;

  const int tid = threadIdx.x;
  const int rowbase = blockIdx.x * ROWS_PER_BLK;

  const float4* w4 = (const float4*)w;
  float4* wl4 = (float4*)wlds;
  #pragma unroll
  for (int i = 0; i < (IN_F * OUT_F / 4) / 256; ++i)
    wl4[tid + i * 256] = w4[tid + i * 256];

  const float4* x4 = (const float4*)(x + (size_t)rowbase * IN_F);
  float4* xl4 = (float4*)xlds;
  #pragma unroll
  for (int i = 0; i < (ROWS_PER_BLK * IN_F / 4) / 256; ++i)
    xl4[tid + i * 256] = x4[tid + i * 256];

  // detect drop_mask storage: 1-byte bool vs int32 (deterministic, data-based)
  if (tid < 64) {
    const unsigned char* m8 = (const unsigned char*)mask;
    unsigned long long b = __ballot(m8[tid] != 0);
    if (tid == 0) mask_is_u8 = (__popcll(b) > 32) ? 1 : 0;
  }
  __syncthreads();

  const int col = tid & 63;
  const int rg  = tid >> 6;  // 0..3, constant per wave

  float acc[8];
  #pragma unroll
  for (int i = 0; i < 8; ++i) acc[i] = 0.0f;

  #pragma unroll 4
  for (int k4 = 0; k4 < IN_F / 4; ++k4) {
    const float w0 = wlds[(4 * k4 + 0) * OUT_F + col];
    const float w1 = wlds[(4 * k4 + 1) * OUT_F + col];
    const float w2 = wlds[(4 * k4 + 2) * OUT_F + col];
    const float w3 = wlds[(4 * k4 + 3) * OUT_F + col];
    #pragma unroll
    for (int i = 0; i < 8; ++i) {
      const float4 xv = *(const float4*)&xlds[(rg + 4 * i) * IN_F + 4 * k4];
      acc[i] = fmaf(xv.x, w0,
               fmaf(xv.y, w1, fmaf(xv.z, w2, fmaf(xv.w, w3, acc[i]))));
    }
  }

  const float bv = bias[col];
  const unsigned char* m8 = (const unsigned char*)mask;
  const int* m32 = (const int*)mask;
  const int u8mode = mask_is_u8;

  #pragma unroll
  for (int i = 0; i < 8; ++i) {
    const int row = rowbase + rg + 4 * i;
    const size_t mi = (size_t)row * OUT_F + col;
    const int keep = u8mode ? (int)m8[mi] : m32[mi];
    const float v = keep ? (acc[i] + bv) * INV_KEEP : 0.0f;
    unsigned u = __float_as_uint(v);
    u += 0x7FFFu + ((u >> 16) & 1u);   // RNE f32->bf16
    hidden[mi] = (ushort)(u >> 16);
  }
}

// ---------------------------------------------------------------------------
// Kernel 2: bucket histogram (LDS-staged)
// ---------------------------------------------------------------------------
__global__ __launch_bounds__(256) void hist_kernel(
    const int* __restrict__ row_idx, int* __restrict__ cnt, int nedges) {
  __shared__ int hc[NB];
  const int t = threadIdx.x;
  for (int i = t; i < NB; i += 256) hc[i] = 0;
  __syncthreads();
  const int stride = gridDim.x * 256;
  for (int e = blockIdx.x * 256 + t; e < nedges; e += stride)
    atomicAdd(&hc[row_idx[e] >> RPB_LOG], 1);
  __syncthreads();
  for (int i = t; i < NB; i += 256)
    if (hc[i]) atomicAdd(&cnt[i], hc[i]);
}

// ---------------------------------------------------------------------------
// Kernel 3: one-block scan of NB counts -> base[NB+1], cursor[NB]
// ---------------------------------------------------------------------------
__global__ __launch_bounds__(1024) void scan_kernel(
    const int* __restrict__ cnt, int* __restrict__ base,
    int* __restrict__ cursor) {
  __shared__ int s[1024];
  const int t = threadIdx.x;
  const int v = (t < NB) ? cnt[t] : 0;
  s[t] = v;
  __syncthreads();
  int a = v;
  #pragma unroll
  for (int d = 1; d < 1024; d <<= 1) {
    const int add = (t >= d) ? s[t - d] : 0;
    __syncthreads();
    a += add;
    s[t] = a;
    __syncthreads();
  }
  if (t < NB) {
    base[t] = a - v;
    cursor[t] = a - v;
  }
  if (t == NB - 1) base[NB] = a;
}

// ---------------------------------------------------------------------------
// Kernel 4: bin — LDS counting-sort a 4096-edge chunk by bucket, then write
// coalesced runs into each bucket's reserved global range.
// meta = ((row & 127) << 17) | col   (24 bits), adj kept f32.
// ---------------------------------------------------------------------------
__global__ __launch_bounds__(BIN_BS) void bin_kernel(
    const int* __restrict__ row_idx, const int* __restrict__ col_idx,
    const float* __restrict__ adj, int* __restrict__ cursor,
    int2* __restrict__ packed, int nedges) {
  __shared__ unsigned sMeta[BIN_CHUNK];   // 16 KB
  __shared__ float    sAdj[BIN_CHUNK];    // 16 KB
  __shared__ ushort   sBkt[BIN_CHUNK];    //  8 KB
  __shared__ int      sCnt[1024];         //  4 KB
  __shared__ int      sScan[1024];        //  4 KB
  __shared__ int      sBase[1024];        //  4 KB
  __shared__ int      sFill[1024];        //  4 KB

  const int t = threadIdx.x;
  const int e0 = blockIdx.x * BIN_CHUNK;
  const int n = min(BIN_CHUNK, nedges - e0);

  sCnt[t] = 0;
  sBase[t] = 0;
  sFill[t] = 0;
  __syncthreads();

  // load my (up to) 4 edges, count buckets
  int      eb[4];
  unsigned em[4];
  float    ea[4];
  #pragma unroll
  for (int j = 0; j < 4; ++j) {
    const int idx = t + j * BIN_BS;
    eb[j] = -1;
    if (idx < n) {
      const int r = row_idx[e0 + idx];
      const int c = col_idx[e0 + idx];
      ea[j] = adj[e0 + idx];
      eb[j] = r >> RPB_LOG;
      em[j] = ((unsigned)(r & (RPB - 1)) << 17) | (unsigned)c;
      atomicAdd(&sCnt[eb[j]], 1);
    }
  }
  __syncthreads();

  // exclusive scan of sCnt (Hillis-Steele over 1024)
  const int v = sCnt[t];
  sScan[t] = v;
  __syncthreads();
  int a = v;
  #pragma unroll
  for (int d = 1; d < 1024; d <<= 1) {
    const int add = (t >= d) ? sScan[t - d] : 0;
    __syncthreads();
    a += add;
    sScan[t] = a;
    __syncthreads();
  }
  const int excl = a - v;
  sScan[t] = excl;  // sScan now holds bucket start within LDS
  // reserve global range for this block's bucket segment
  if (v > 0 && t < NB) sBase[t] = atomicAdd(&cursor[t], v);
  __syncthreads();

  // scatter into sorted LDS positions (LDS random writes are cheap)
  #pragma unroll
  for (int j = 0; j < 4; ++j) {
    if (eb[j] >= 0) {
      const int p = sScan[eb[j]] + atomicAdd(&sFill[eb[j]], 1);
      sMeta[p] = em[j];
      sAdj[p] = ea[j];
      sBkt[p] = (ushort)eb[j];
    }
  }
  __syncthreads();

  // write out: consecutive sorted positions -> consecutive global positions
  #pragma unroll
  for (int j = 0; j < 4; ++j) {
    const int sp = t + j * BIN_BS;
    if (sp < n) {
      const int b = sBkt[sp];
      const int dst = sBase[b] + (sp - sScan[b]);
      int2 o;
      o.x = (int)sMeta[sp];
      o.y = __float_as_int(sAdj[sp]);
      packed[dst] = o;
    }
  }
}

// ---------------------------------------------------------------------------
// Kernel 5: bucket accumulate. Block per bucket; 32 KB LDS f32 acc
// [128 rows][64 feats]. Contiguous edge reads, bf16 gathers (L3), ds_add_f32,
// then one coalesced ReLU float4 store of the 32 KB tile.
// ---------------------------------------------------------------------------
__global__ __launch_bounds__(256) void bucket_acc_kernel(
    const int* __restrict__ base, const int2* __restrict__ packed,
    const ushort* __restrict__ hidden, float* __restrict__ out) {
  __shared__ float acc[RPB * OUT_F];  // 32 KB

  const int t = threadIdx.x;
  const int b = blockIdx.x;
  const int lane = t & 63;
  const int wv = t >> 6;  // 0..3

  float4* a4 = (float4*)acc;
  #pragma unroll
  for (int i = 0; i < (RPB * OUT_F / 4) / 256; ++i)
    a4[t + i * 256] = make_float4(0.f, 0.f, 0.f, 0.f);
  __syncthreads();

  const int s = base[b];
  const int e = base[b + 1];

  // each wave strides 8-edge groups; 8 gathers in flight (MLP)
  for (int i = s + wv * 8; i < e; i += 32) {
    int2 q[8];
    #pragma unroll
    for (int j = 0; j < 8; ++j)
      q[j] = (i + j < e) ? packed[i + j] : make_int2(0, 0);
    float h[8];
    #pragma unroll
    for (int j = 0; j < 8; ++j) {
      const int c = q[j].x & 0x1FFFF;
      const ushort u = hidden[(size_t)c * OUT_F + lane];
      h[j] = __uint_as_float((unsigned)u << 16);
    }
    #pragma unroll
    for (int j = 0; j < 8; ++j) {
      const int ro = (q[j].x >> 17) & (RPB - 1);
      const float av = __int_as_float(q[j].y);
      atomicAdd(&acc[ro * OUT_F + lane], av * h[j]);
    }
  }
  __syncthreads();

  // write tile with fused ReLU (float4, coalesced); guard tail rows
  const int rbase = b * RPB;
  float4* o4 = (float4*)(out + (size_t)rbase * OUT_F);
  #pragma unroll
  for (int i = 0; i < (RPB * OUT_F / 4) / 256; ++i) {
    const int idx4 = t + i * 256;
    const int r = idx4 >> 4;  // 16 float4 per row
    if (rbase + r < N_NODES) {
      float4 vv = a4[idx4];
      vv.x = fmaxf(vv.x, 0.f);
      vv.y = fmaxf(vv.y, 0.f);
      vv.z = fmaxf(vv.z, 0.f);
      vv.w = fmaxf(vv.w, 0.f);
      o4[idx4] = vv;
    }
  }
}

extern "C" void kernel_launch(void* const* d_in, const int* in_sizes, int n_in,
                              void* d_out, int out_size, void* d_ws,
                              size_t ws_size, hipStream_t stream) {
  const float* x       = (const float*)d_in[0];
  const int*   row_idx = (const int*)d_in[1];
  const int*   col_idx = (const int*)d_in[2];
  const float* adj     = (const float*)d_in[3];
  const void*  mask    = d_in[4];
  const float* w       = (const float*)d_in[5];
  const float* bias    = (const float*)d_in[6];
  float* out = (float*)d_out;
  const int nedges = in_sizes[1];

  // ws layout (16B-aligned): hidden bf16 | cnt | base | cursor | packed
  char* ws = (char*)d_ws;
  const size_t off_hidden = 0;
  const size_t sz_hidden  = (size_t)N_NODES * OUT_F * sizeof(ushort);  // 12.8MB
  const size_t off_cnt    = (off_hidden + sz_hidden + 15) & ~(size_t)15;
  const size_t off_base   = (off_cnt + NB * 4 + 15) & ~(size_t)15;
  const size_t off_cursor = (off_base + (NB + 1) * 4 + 15) & ~(size_t)15;
  const size_t off_packed = (off_cursor + NB * 4 + 15) & ~(size_t)15;

  ushort* hidden = (ushort*)(ws + off_hidden);
  int*    cnt    = (int*)(ws + off_cnt);
  int*    base   = (int*)(ws + off_base);
  int*    cursor = (int*)(ws + off_cursor);
  int2*   packed = (int2*)(ws + off_packed);

  gemm_dropout_kernel<<<N_NODES / ROWS_PER_BLK, 256, 0, stream>>>(
      x, w, bias, mask, hidden);

  hipMemsetAsync(cnt, 0, NB * 4, stream);
  hist_kernel<<<512, 256, 0, stream>>>(row_idx, cnt, nedges);
  scan_kernel<<<1, 1024, 0, stream>>>(cnt, base, cursor);
  bin_kernel<<<(nedges + BIN_CHUNK - 1) / BIN_CHUNK, BIN_BS, 0, stream>>>(
      row_idx, col_idx, adj, cursor, packed, nedges);
  bucket_acc_kernel<<<NB, 256, 0, stream>>>(base, packed, hidden, out);
}